// Round 9
// baseline (472.537 us; speedup 1.0000x reference)
//
#include <hip/hip_runtime.h>
#include <hip/hip_bf16.h>

// ObjectAttentionBlock on MI355X, round 9.
// r8 = 371.7us. XCD co-location gave only -5.5us -> ctxT re-reads were already
// L3-absorbed; G_up's cost is structural (2-barrier loop, 4 K-steps). This
// round: G_up -> gup_stream, a barrier-free streaming kernel: 128-co Wu panel
// staged ONCE in LDS (64KB, XOR-swizzled via pre-swizzled gload_lds source),
// then stream 8 pixel-tiles with zero syncs: direct-global coalesced B-frags
// (8-deep ILP) x LDS A-frags (2-way conflict = free). 4 m-panel sharers of a
// pixel-group co-located per XCD. Everything else unchanged from r8.

typedef __bf16 bf16x8 __attribute__((ext_vector_type(8)));
typedef float f32x4 __attribute__((ext_vector_type(4)));

#define AS1 __attribute__((address_space(1)))
#define AS3 __attribute__((address_space(3)))
#define MFMA_16x16x32(a, b, c) __builtin_amdgcn_mfma_f32_16x16x32_bf16((a), (b), (c), 0, 0, 0)

__device__ __forceinline__ unsigned short f2bf(float f) {
  union { float f; unsigned u; } x; x.f = f;
  unsigned r = (x.u + 0x7FFFu + ((x.u >> 16) & 1u)) >> 16;  // RNE
  return (unsigned short)r;
}

// ---------------- merged weight cast ----------------
__global__ __launch_bounds__(256) void cast_weights(
    const float* __restrict__ w1, const float* __restrict__ w2,
    const float* __restrict__ wu, unsigned short* __restrict__ W1b,
    unsigned short* __restrict__ W2b, unsigned short* __restrict__ Wub) {
  int i = blockIdx.x * 256 + threadIdx.x;   // grid 1280 -> 327680 items
  if (i < 131072) W1b[i] = f2bf(w1[i]);
  else if (i < 196608) W2b[i - 131072] = f2bf(w2[i - 131072]);
  else if (i < 327680) Wub[i - 196608] = f2bf(wu[i - 196608]);
}

// ---------------- key/value kernel (fp32 math, tiny) ----------------
__global__ __launch_bounds__(256) void kv_kernel(
    const float* __restrict__ proxy,
    const float* __restrict__ w_fo1, const float* __restrict__ b_fo1,
    const float* __restrict__ w_fo2, const float* __restrict__ b_fo2,
    const float* __restrict__ w_fd, const float* __restrict__ b_fd,
    unsigned short* __restrict__ keyT, unsigned short* __restrict__ Vv) {
  __shared__ float cols[512][8];
  __shared__ float k1s[256][8];
  const int b = blockIdx.y;
  const int p0 = blockIdx.x * 8;      // 20 chunks cover p 0..159
  const int t = threadIdx.x;
#pragma unroll
  for (int i = 0; i < 8; i++) {
    int idx = t + i * 256;
    int c = idx >> 2, q = idx & 3;
    int p = p0 + q * 2;
    float2 v = make_float2(0.f, 0.f);
    if (p < 150) v = *(const float2*)(proxy + ((size_t)b * 512 + c) * 150 + p);
    cols[c][q * 2 + 0] = v.x;
    cols[c][q * 2 + 1] = v.y;
  }
  __syncthreads();
  float accV[8], accK[8];
  {
    float bv = b_fd[t], bk = b_fo1[t];
#pragma unroll
    for (int px = 0; px < 8; px++) { accV[px] = bv; accK[px] = bk; }
  }
#define KV_FMA(j, wv_, wk_)                                      \
  { float4 ca = *(const float4*)&cols[c + j][0];                 \
    float4 cb = *(const float4*)&cols[c + j][4];                 \
    accV[0] += wv_ * ca.x; accV[1] += wv_ * ca.y;                \
    accV[2] += wv_ * ca.z; accV[3] += wv_ * ca.w;                \
    accV[4] += wv_ * cb.x; accV[5] += wv_ * cb.y;                \
    accV[6] += wv_ * cb.z; accV[7] += wv_ * cb.w;                \
    accK[0] += wk_ * ca.x; accK[1] += wk_ * ca.y;                \
    accK[2] += wk_ * ca.z; accK[3] += wk_ * ca.w;                \
    accK[4] += wk_ * cb.x; accK[5] += wk_ * cb.y;                \
    accK[6] += wk_ * cb.z; accK[7] += wk_ * cb.w; }
  for (int c = 0; c < 512; c += 4) {
    float4 wv4 = *(const float4*)(w_fd + (size_t)t * 512 + c);
    float4 wk4 = *(const float4*)(w_fo1 + (size_t)t * 512 + c);
    KV_FMA(0, wv4.x, wk4.x)
    KV_FMA(1, wv4.y, wk4.y)
    KV_FMA(2, wv4.z, wk4.z)
    KV_FMA(3, wv4.w, wk4.w)
  }
#pragma unroll
  for (int px = 0; px < 8; px++) {
    Vv[((size_t)b * 256 + t) * 160 + p0 + px] = f2bf(fmaxf(accV[px], 0.f));
    k1s[t][px] = fmaxf(accK[px], 0.f);
  }
  __syncthreads();
  float accY[8];
  {
    float by = b_fo2[t];
#pragma unroll
    for (int px = 0; px < 8; px++) accY[px] = by;
  }
#define KV_FMA2(j, wy_)                                          \
  { float4 ca = *(const float4*)&k1s[c + j][0];                  \
    float4 cb = *(const float4*)&k1s[c + j][4];                  \
    accY[0] += wy_ * ca.x; accY[1] += wy_ * ca.y;                \
    accY[2] += wy_ * ca.z; accY[3] += wy_ * ca.w;                \
    accY[4] += wy_ * cb.x; accY[5] += wy_ * cb.y;                \
    accY[6] += wy_ * cb.z; accY[7] += wy_ * cb.w; }
  for (int c = 0; c < 256; c += 4) {
    float4 wy4 = *(const float4*)(w_fo2 + (size_t)t * 256 + c);
    KV_FMA2(0, wy4.x)
    KV_FMA2(1, wy4.y)
    KV_FMA2(2, wy4.z)
    KV_FMA2(3, wy4.w)
  }
#pragma unroll
  for (int px = 0; px < 8; px++)
    keyT[((size_t)b * 160 + p0 + px) * 256 + t] = f2bf(fmaxf(accY[px], 0.f));
}

// ---------------- GEMM1 fused transpose: q1T = relu(x^T @ W1^T + b1) ----------------
__global__ __launch_bounds__(256, 3) void gemm1_fused(
    const float* __restrict__ X, const unsigned short* __restrict__ Bt,
    const float* __restrict__ bias, unsigned short* __restrict__ Cq) {
  const int HW = 16384, K = 512, N = 256;
  __shared__ float Af[64 * 128];
  __shared__ unsigned short Bs[128 * 64];
  const int r = blockIdx.x;                 // 0..255
  const int b = blockIdx.y;
  const int my = ((r >> 4) << 3) | (r & 7); // 0..127
  const int nx = (r >> 3) & 1;
  const int m0 = my * 128, n0 = nx * 128;
  const int tid = threadIdx.x;
  const int w = tid >> 6, l = tid & 63;
  const int lr = l & 15, lg = l >> 4;
  const int wm = (w >> 1) * 64, wn = (w & 1) * 64;
  const float* Xb = X + (size_t)b * K * HW;
  const unsigned short* Btb = Bt + (size_t)n0 * K;
  const f32x4 zero = {0.f, 0.f, 0.f, 0.f};
  f32x4 acc[4][4];
#pragma unroll
  for (int m = 0; m < 4; m++)
#pragma unroll
    for (int n = 0; n < 4; n++) acc[m][n] = zero;

  const int arow = l >> 5, acol = l & 31;
  const int bsub = l >> 3, bcol = (l & 7) * 8;
  for (int kt = 0; kt < K; kt += 64) {
    __syncthreads();
#pragma unroll
    for (int i = 0; i < 8; i++) {
      const int rk = w * 16 + i * 2 + arow;
      const int s = (rk >> 3) & 7;
      __builtin_amdgcn_global_load_lds(
          (AS1 void*)(Xb + (size_t)(kt + rk) * HW + m0 + ((acol ^ s) << 2)),
          (AS3 void*)(Af + (w * 16 + i * 2) * 128), 16, 0, 0);
    }
#pragma unroll
    for (int i = 0; i < 4; i++) {
      __builtin_amdgcn_global_load_lds(
          (AS1 void*)(Btb + (size_t)(w * 32 + i * 8 + bsub) * K + kt + bcol),
          (AS3 void*)(Bs + (w * 32 + i * 8) * 64), 16, 0, 0);
    }
    __syncthreads();
#pragma unroll
    for (int ks = 0; ks < 2; ks++) {
      bf16x8 aF[4], bF[4];
      const int s = ks * 4 + lg;
#pragma unroll
      for (int m = 0; m < 4; m++) {
        const int p = wm + m * 16 + lr;
        const int cb = ((((p >> 2) ^ s) << 2) | (p & 3));
        bf16x8 a;
#pragma unroll
        for (int j = 0; j < 8; j++)
          a[j] = (__bf16)Af[(ks * 32 + lg * 8 + j) * 128 + cb];
        aF[m] = a;
      }
#pragma unroll
      for (int n = 0; n < 4; n++)
        bF[n] = *(const bf16x8*)(Bs + (wn + n * 16 + lr) * 64 + ks * 32 + lg * 8);
#pragma unroll
      for (int m = 0; m < 4; m++)
#pragma unroll
        for (int n = 0; n < 4; n++) acc[m][n] = MFMA_16x16x32(aF[m], bF[n], acc[m][n]);
    }
  }
  unsigned short* Cb = Cq + (size_t)b * HW * N;
#pragma unroll
  for (int m = 0; m < 4; m++) {
#pragma unroll
    for (int n = 0; n < 4; n++) {
      const int col = n0 + wn + n * 16 + lr;
      const float bc = bias[col];
#pragma unroll
      for (int r2 = 0; r2 < 4; r2++) {
        const int row = m0 + wm + m * 16 + lg * 4 + r2;
        Cb[(size_t)row * N + col] = f2bf(fmaxf(acc[m][n][r2] + bc, 0.f));
      }
    }
  }
}

// ---------------- generic bf16 GEMM (used for G2): C = relu(A @ Bt^T + bias) ----------------
// COLOC=1: 1D grid, n-pairs sharing an A-tile co-located on one XCD.
template <int BIAS_ROW, int OUTF32, int COLOC>
__global__ __launch_bounds__(256, 4) void gemm_bt_relu(
    const unsigned short* __restrict__ A, const unsigned short* __restrict__ Bt,
    const float* __restrict__ bias, void* __restrict__ Cout,
    int M, int N, int K, long long sA, long long sB, long long sC) {
  __shared__ unsigned short As[128 * 64];
  __shared__ unsigned short Bs[128 * 64];
  int m0, n0, b;
  if (COLOC == 1) {            // M=16384 (128 tiles), N=256 (2 tiles), B=8
    const int g = blockIdx.x, x = g & 7, j = g >> 3;
    const int og = ((j >> 1) << 3) | x;      // (pix,b) id, 0..1023
    n0 = (j & 1) * 128; m0 = (og & 127) * 128; b = og >> 7;
  } else {
    b = blockIdx.z; m0 = blockIdx.x * 128; n0 = blockIdx.y * 128;
  }
  const int tid = threadIdx.x;
  const int w = tid >> 6, l = tid & 63;
  const int lr = l & 15, lg = l >> 4;
  const int wm = (w >> 1) * 64, wn = (w & 1) * 64;
  const unsigned short* Ab = A + (size_t)b * sA + (size_t)m0 * K;
  const unsigned short* Btb = Bt + (size_t)b * sB + (size_t)n0 * K;
  const f32x4 zero = {0.f, 0.f, 0.f, 0.f};
  f32x4 acc[4][4];
#pragma unroll
  for (int m = 0; m < 4; m++)
#pragma unroll
    for (int n = 0; n < 4; n++) acc[m][n] = zero;

  const int srow = w * 32 + (l >> 3);
  const int scol = (l & 7) * 8;
  for (int kt = 0; kt < K; kt += 64) {
    __syncthreads();
#pragma unroll
    for (int i = 0; i < 4; i++) {
      __builtin_amdgcn_global_load_lds(
          (AS1 void*)(Ab + (size_t)(srow + i * 8) * K + kt + scol),
          (AS3 void*)(As + (w * 32 + i * 8) * 64), 16, 0, 0);
      __builtin_amdgcn_global_load_lds(
          (AS1 void*)(Btb + (size_t)(srow + i * 8) * K + kt + scol),
          (AS3 void*)(Bs + (w * 32 + i * 8) * 64), 16, 0, 0);
    }
    __syncthreads();
#pragma unroll
    for (int ks = 0; ks < 2; ks++) {
      bf16x8 aF[4], bF[4];
#pragma unroll
      for (int m = 0; m < 4; m++)
        aF[m] = *(const bf16x8*)(As + (wm + m * 16 + lr) * 64 + ks * 32 + lg * 8);
#pragma unroll
      for (int n = 0; n < 4; n++)
        bF[n] = *(const bf16x8*)(Bs + (wn + n * 16 + lr) * 64 + ks * 32 + lg * 8);
#pragma unroll
      for (int m = 0; m < 4; m++)
#pragma unroll
        for (int n = 0; n < 4; n++) acc[m][n] = MFMA_16x16x32(aF[m], bF[n], acc[m][n]);
    }
  }
#pragma unroll
  for (int m = 0; m < 4; m++) {
#pragma unroll
    for (int n = 0; n < 4; n++) {
      const int col = n0 + wn + n * 16 + lr;
      const float bc = BIAS_ROW ? 0.f : bias[col];
#pragma unroll
      for (int r = 0; r < 4; r++) {
        const int row = m0 + wm + m * 16 + lg * 4 + r;
        float v = acc[m][n][r] + (BIAS_ROW ? bias[row] : bc);
        v = fmaxf(v, 0.f);
        if (OUTF32)
          ((float*)Cout)[(size_t)b * sC + (size_t)row * N + col] = v;
        else
          ((unsigned short*)Cout)[(size_t)b * sC + (size_t)row * N + col] = f2bf(v);
      }
    }
  }
}

// ---------------- fused attention: ctxT = softmax(Q Kt^T /16) @ V ----------------
__global__ __launch_bounds__(256, 4) void attn_kernel(
    const unsigned short* __restrict__ Q, const unsigned short* __restrict__ Kt,
    const unsigned short* __restrict__ Vv, unsigned short* __restrict__ ctxT) {
  const int HW = 16384;
  __shared__ unsigned short Pls[128 * 160];
  const int b = blockIdx.y;
  const int pix0 = blockIdx.x * 128;
  const int tid = threadIdx.x;
  const int w = tid >> 6, l = tid & 63;
  const int lr = l & 15, lg = l >> 4;
  const unsigned short* Qb = Q + ((size_t)b * HW + pix0 + w * 32) * 256;
  const unsigned short* Kb = Kt + (size_t)b * 160 * 256;
  const unsigned short* Vb = Vv + (size_t)b * 256 * 160;
  const f32x4 zero = {0.f, 0.f, 0.f, 0.f};

  f32x4 acc[2][10];
#pragma unroll
  for (int m = 0; m < 2; m++)
#pragma unroll
    for (int n = 0; n < 10; n++) acc[m][n] = zero;
#pragma unroll 2
  for (int ks = 0; ks < 8; ks++) {
    bf16x8 aF[2];
#pragma unroll
    for (int m = 0; m < 2; m++)
      aF[m] = *(const bf16x8*)(Qb + (size_t)(m * 16 + lr) * 256 + ks * 32 + lg * 8);
#pragma unroll
    for (int n = 0; n < 10; n++) {
      bf16x8 bF = *(const bf16x8*)(Kb + (size_t)(n * 16 + lr) * 256 + ks * 32 + lg * 8);
      acc[0][n] = MFMA_16x16x32(aF[0], bF, acc[0][n]);
      acc[1][n] = MFMA_16x16x32(aF[1], bF, acc[1][n]);
    }
  }
  const float scale = 0.0625f;  // 1/sqrt(256)
#pragma unroll
  for (int m = 0; m < 2; m++) {
#pragma unroll
    for (int r = 0; r < 4; r++) {
      float lm = -1e30f;
#pragma unroll
      for (int n = 0; n < 10; n++) {
        float v = acc[m][n][r] * scale;
        acc[m][n][r] = v;
        if (n * 16 + lr < 150) lm = fmaxf(lm, v);
      }
#pragma unroll
      for (int msk = 1; msk <= 8; msk <<= 1) lm = fmaxf(lm, __shfl_xor(lm, msk, 64));
      float s = 0.f;
#pragma unroll
      for (int n = 0; n < 10; n++) {
        float p = (n * 16 + lr < 150) ? __expf(acc[m][n][r] - lm) : 0.f;
        acc[m][n][r] = p;
        s += p;
      }
#pragma unroll
      for (int msk = 1; msk <= 8; msk <<= 1) s += __shfl_xor(s, msk, 64);
      float inv = 1.f / s;
      const int row = w * 32 + m * 16 + lg * 4 + r;
      const unsigned sw = (unsigned)(row & 7) << 4;
#pragma unroll
      for (int n = 0; n < 10; n++) {
        unsigned boff = (unsigned)row * 320 + (unsigned)(n * 16 + lr) * 2;
        *(unsigned short*)((char*)Pls + (boff ^ sw)) = f2bf(acc[m][n][r] * inv);
      }
    }
  }
  __syncthreads();
  unsigned short* Cb = ctxT + ((size_t)b * HW + pix0 + w * 32) * 256;
#pragma unroll
  for (int half = 0; half < 2; half++) {
    f32x4 acc2[2][8];
#pragma unroll
    for (int m = 0; m < 2; m++)
#pragma unroll
      for (int n = 0; n < 8; n++) acc2[m][n] = zero;
    for (int ks = 0; ks < 5; ks++) {
      bf16x8 aP[2];
#pragma unroll
      for (int m = 0; m < 2; m++) {
        const int row = w * 32 + m * 16 + lr;
        unsigned boff = (unsigned)row * 320 + (unsigned)(ks * 64 + lg * 16);
        aP[m] = *(const bf16x8*)((const char*)Pls + (boff ^ ((unsigned)(row & 7) << 4)));
      }
#pragma unroll
      for (int n = 0; n < 8; n++) {
        const int ch = half * 128 + n * 16 + lr;
        bf16x8 bV = *(const bf16x8*)(Vb + (size_t)ch * 160 + ks * 32 + lg * 8);
        acc2[0][n] = MFMA_16x16x32(aP[0], bV, acc2[0][n]);
        acc2[1][n] = MFMA_16x16x32(aP[1], bV, acc2[1][n]);
      }
    }
#pragma unroll
    for (int m = 0; m < 2; m++)
#pragma unroll
      for (int n = 0; n < 8; n++)
#pragma unroll
        for (int r = 0; r < 4; r++)
          Cb[(size_t)(m * 16 + lg * 4 + r) * 256 + half * 128 + n * 16 + lr] =
              f2bf(acc2[m][n][r]);
  }
}

// ---------------- G_up streaming: out = relu(Wu @ ctx^T + bu), fp32 ----------------
// Block: 128-co Wu panel in LDS (loaded once, swizzled), streams 8 tiles of
// 128 pixels. No barriers in the stream loop. Grid 512 = bijective remap so
// the 4 m-panels sharing a pixel-group are co-resident on one XCD.
__global__ __launch_bounds__(256, 2) void gup_stream(
    const unsigned short* __restrict__ Wu, const unsigned short* __restrict__ ctxT,
    const float* __restrict__ bu, float* __restrict__ Out) {
  const int HW = 16384;
  __shared__ __align__(16) unsigned short Als[128 * 256];   // 64 KB
  // decode: pair=(b*16+pg) 0..127; flat = ((pair>>3)*4 + mp)*8 + (pair&7)
  const int g = blockIdx.x;            // 0..511
  const int xcd = g & 7, j = g >> 3;   // j 0..63
  const int mp = j & 3, pairhi = j >> 2;
  const int pair = (pairhi << 3) | xcd;
  const int b = pair >> 4, pg = pair & 15;
  const int m0 = mp * 128;
  const int tid = (int)threadIdx.x;
  const int w = tid >> 6, l = tid & 63;
  const int lr = l & 15, lg = l >> 4;
  const f32x4 zero = {0.f, 0.f, 0.f, 0.f};

  // ---- one-time A panel load: LDS[co*512 + t*16] = Wu[m0+co][(t^(co&7))*8..]
  {
    const int lco = l >> 5;            // row within op (2 rows/op)
    const int t16 = l & 31;            // 16B slot within row
#pragma unroll
    for (int i = 0; i < 16; i++) {
      const int op = w * 16 + i;       // 0..63
      const int co = op * 2 + lco;     // 0..127
      const int src16 = t16 ^ (co & 7);
      __builtin_amdgcn_global_load_lds(
          (AS1 void*)(Wu + (size_t)(m0 + co) * 256 + src16 * 8),
          (AS3 void*)((char*)Als + op * 1024), 16, 0, 0);
    }
  }
  __syncthreads();

  const int wm = w * 32;               // wave owns 32 co rows
  const unsigned short* Cb = ctxT + (size_t)b * HW * 256;
  float* Ob = Out + (size_t)b * 512 * HW + (size_t)m0 * HW;

#pragma unroll 1
  for (int t = 0; t < 8; t++) {
    const int pix0 = pg * 1024 + t * 128;
    f32x4 acc[2][8];
#pragma unroll
    for (int m = 0; m < 2; m++)
#pragma unroll
      for (int n = 0; n < 8; n++) acc[m][n] = zero;
#pragma unroll
    for (int ks = 0; ks < 8; ks++) {
      bf16x8 aF[2];
#pragma unroll
      for (int m = 0; m < 2; m++) {
        const int co = wm + m * 16 + lr;
        const unsigned boff =
            ((unsigned)co << 9) + ((unsigned)(((ks << 2) + lg) ^ (co & 7)) << 4);
        aF[m] = *(const bf16x8*)((const char*)Als + boff);
      }
#pragma unroll
      for (int n = 0; n < 8; n++) {
        bf16x8 bF = *(const bf16x8*)(Cb + (size_t)(pix0 + n * 16 + lr) * 256 +
                                     ks * 32 + lg * 8);
        acc[0][n] = MFMA_16x16x32(aF[0], bF, acc[0][n]);
        acc[1][n] = MFMA_16x16x32(aF[1], bF, acc[1][n]);
      }
    }
#pragma unroll
    for (int m = 0; m < 2; m++) {
#pragma unroll
      for (int r = 0; r < 4; r++) {
        const int co = wm + m * 16 + lg * 4 + r;
        const float bb = bu[m0 + co];
#pragma unroll
        for (int n = 0; n < 8; n++)
          Ob[(size_t)co * HW + pix0 + n * 16 + lr] = fmaxf(acc[m][n][r] + bb, 0.f);
      }
    }
  }
}

// ---------------- host launcher ----------------
extern "C" void kernel_launch(void* const* d_in, const int* in_sizes, int n_in,
                              void* d_out, int out_size, void* d_ws, size_t ws_size,
                              hipStream_t stream) {
  (void)in_sizes; (void)n_in; (void)out_size;
  const float* x     = (const float*)d_in[0];
  const float* proxy = (const float*)d_in[1];
  const float* w_fp1 = (const float*)d_in[2];
  const float* b_fp1 = (const float*)d_in[3];
  const float* w_fp2 = (const float*)d_in[4];
  const float* b_fp2 = (const float*)d_in[5];
  const float* w_fo1 = (const float*)d_in[6];
  const float* b_fo1 = (const float*)d_in[7];
  const float* w_fo2 = (const float*)d_in[8];
  const float* b_fo2 = (const float*)d_in[9];
  const float* w_fd  = (const float*)d_in[10];
  const float* b_fd  = (const float*)d_in[11];
  const float* w_fu  = (const float*)d_in[12];
  const float* b_fu  = (const float*)d_in[13];

  char* ws = (char*)d_ws;
  unsigned short* W1b  = (unsigned short*)(ws + 0);          // 256x512 bf16
  unsigned short* W2b  = (unsigned short*)(ws + 262144);     // 256x256
  unsigned short* Wub  = (unsigned short*)(ws + 393216);     // 512x256
  unsigned short* keyT = (unsigned short*)(ws + 655360);     // [8][160][256]
  unsigned short* Vv   = (unsigned short*)(ws + 1310720);    // [8][256][160]
  unsigned short* bufA = (unsigned short*)(ws + 2097152);    // q2T
  unsigned short* bufB = (unsigned short*)(ws + 2097152 + 134217728);  // q1T, later ctxT
  if (ws_size < 203423744) return;

  dim3 blk(256);
  cast_weights<<<1280, blk, 0, stream>>>(w_fp1, w_fp2, w_fu, W1b, W2b, Wub);
  kv_kernel<<<dim3(20, 8), blk, 0, stream>>>(proxy, w_fo1, b_fo1, w_fo2, b_fo2,
                                             w_fd, b_fd, keyT, Vv);
  // q1 = relu(x^T @ W1^T + b1) with fused transpose -> bufB
  gemm1_fused<<<dim3(256, 8), blk, 0, stream>>>(x, W1b, b_fp1, bufB);
  // q2 = relu(q1 @ W2^T + b2) -> bufA   [XCD co-located n-pairs]
  gemm_bt_relu<0, 0, 1><<<2048, blk, 0, stream>>>(
      bufB, W2b, b_fp2, bufA, 16384, 256, 256,
      (long long)16384 * 256, 0, (long long)16384 * 256);
  // ctxT = softmax(q2 keyT^T / 16) @ V -> bufB
  attn_kernel<<<dim3(128, 8), blk, 0, stream>>>(bufA, keyT, Vv, bufB);
  // out = relu(Wu @ ctxT^T + bu), fp32 channels-first, streaming kernel
  gup_stream<<<512, blk, 0, stream>>>(Wub, bufB, b_fu, (float*)d_out);
}

// Round 10
// 392.335 us; speedup vs baseline: 1.2044x; 1.2044x over previous
//
#include <hip/hip_runtime.h>
#include <hip/hip_bf16.h>

// ObjectAttentionBlock on MI355X, round 10.
// r9 gup_stream regressed (176us; ctxT reads were already cache-hits, FETCH
// 34MB -> nothing to save; lost parallelism). Revert G_up to r8's proven
// gemm_bt_relu (75us). ONE new change: head_kernel = gemm1(N=256) + G2 fused;
// q1 lives only in LDS (64KB, XOR-swizzled), W2 streamed from L2 with 16-deep
// load batches at VGPR<=256 (r8-attn pattern, not r7's starved one). Kills
// q1's 268MB round-trip + 1 launch.

typedef __bf16 bf16x8 __attribute__((ext_vector_type(8)));
typedef float f32x4 __attribute__((ext_vector_type(4)));

#define AS1 __attribute__((address_space(1)))
#define AS3 __attribute__((address_space(3)))
#define MFMA_16x16x32(a, b, c) __builtin_amdgcn_mfma_f32_16x16x32_bf16((a), (b), (c), 0, 0, 0)

__device__ __forceinline__ unsigned short f2bf(float f) {
  union { float f; unsigned u; } x; x.f = f;
  unsigned r = (x.u + 0x7FFFu + ((x.u >> 16) & 1u)) >> 16;  // RNE
  return (unsigned short)r;
}

// ---------------- merged weight cast ----------------
__global__ __launch_bounds__(256) void cast_weights(
    const float* __restrict__ w1, const float* __restrict__ w2,
    const float* __restrict__ wu, unsigned short* __restrict__ W1b,
    unsigned short* __restrict__ W2b, unsigned short* __restrict__ Wub) {
  int i = blockIdx.x * 256 + threadIdx.x;   // grid 1280 -> 327680 items
  if (i < 131072) W1b[i] = f2bf(w1[i]);
  else if (i < 196608) W2b[i - 131072] = f2bf(w2[i - 131072]);
  else if (i < 327680) Wub[i - 196608] = f2bf(wu[i - 196608]);
}

// ---------------- key/value kernel (fp32 math, tiny) ----------------
__global__ __launch_bounds__(256) void kv_kernel(
    const float* __restrict__ proxy,
    const float* __restrict__ w_fo1, const float* __restrict__ b_fo1,
    const float* __restrict__ w_fo2, const float* __restrict__ b_fo2,
    const float* __restrict__ w_fd, const float* __restrict__ b_fd,
    unsigned short* __restrict__ keyT, unsigned short* __restrict__ Vv) {
  __shared__ float cols[512][8];
  __shared__ float k1s[256][8];
  const int b = blockIdx.y;
  const int p0 = blockIdx.x * 8;      // 20 chunks cover p 0..159
  const int t = threadIdx.x;
#pragma unroll
  for (int i = 0; i < 8; i++) {
    int idx = t + i * 256;
    int c = idx >> 2, q = idx & 3;
    int p = p0 + q * 2;
    float2 v = make_float2(0.f, 0.f);
    if (p < 150) v = *(const float2*)(proxy + ((size_t)b * 512 + c) * 150 + p);
    cols[c][q * 2 + 0] = v.x;
    cols[c][q * 2 + 1] = v.y;
  }
  __syncthreads();
  float accV[8], accK[8];
  {
    float bv = b_fd[t], bk = b_fo1[t];
#pragma unroll
    for (int px = 0; px < 8; px++) { accV[px] = bv; accK[px] = bk; }
  }
#define KV_FMA(j, wv_, wk_)                                      \
  { float4 ca = *(const float4*)&cols[c + j][0];                 \
    float4 cb = *(const float4*)&cols[c + j][4];                 \
    accV[0] += wv_ * ca.x; accV[1] += wv_ * ca.y;                \
    accV[2] += wv_ * ca.z; accV[3] += wv_ * ca.w;                \
    accV[4] += wv_ * cb.x; accV[5] += wv_ * cb.y;                \
    accV[6] += wv_ * cb.z; accV[7] += wv_ * cb.w;                \
    accK[0] += wk_ * ca.x; accK[1] += wk_ * ca.y;                \
    accK[2] += wk_ * ca.z; accK[3] += wk_ * ca.w;                \
    accK[4] += wk_ * cb.x; accK[5] += wk_ * cb.y;                \
    accK[6] += wk_ * cb.z; accK[7] += wk_ * cb.w; }
  for (int c = 0; c < 512; c += 4) {
    float4 wv4 = *(const float4*)(w_fd + (size_t)t * 512 + c);
    float4 wk4 = *(const float4*)(w_fo1 + (size_t)t * 512 + c);
    KV_FMA(0, wv4.x, wk4.x)
    KV_FMA(1, wv4.y, wk4.y)
    KV_FMA(2, wv4.z, wk4.z)
    KV_FMA(3, wv4.w, wk4.w)
  }
#pragma unroll
  for (int px = 0; px < 8; px++) {
    Vv[((size_t)b * 256 + t) * 160 + p0 + px] = f2bf(fmaxf(accV[px], 0.f));
    k1s[t][px] = fmaxf(accK[px], 0.f);
  }
  __syncthreads();
  float accY[8];
  {
    float by = b_fo2[t];
#pragma unroll
    for (int px = 0; px < 8; px++) accY[px] = by;
  }
#define KV_FMA2(j, wy_)                                          \
  { float4 ca = *(const float4*)&k1s[c + j][0];                  \
    float4 cb = *(const float4*)&k1s[c + j][4];                  \
    accY[0] += wy_ * ca.x; accY[1] += wy_ * ca.y;                \
    accY[2] += wy_ * ca.z; accY[3] += wy_ * ca.w;                \
    accY[4] += wy_ * cb.x; accY[5] += wy_ * cb.y;                \
    accY[6] += wy_ * cb.z; accY[7] += wy_ * cb.w; }
  for (int c = 0; c < 256; c += 4) {
    float4 wy4 = *(const float4*)(w_fo2 + (size_t)t * 256 + c);
    KV_FMA2(0, wy4.x)
    KV_FMA2(1, wy4.y)
    KV_FMA2(2, wy4.z)
    KV_FMA2(3, wy4.w)
  }
#pragma unroll
  for (int px = 0; px < 8; px++)
    keyT[((size_t)b * 160 + p0 + px) * 256 + t] = f2bf(fmaxf(accY[px], 0.f));
}

// ---------------- HEAD: q2 = relu(relu(x^T W1^T + b1) W2^T + b2) ----------------
// Per block: 128 pixels, 4 waves, LDS 64KB (Af 32K f32 + Bs 32K bf16, then
// q1s 64KB aliases both). Phase 1 = gemm1_fused widened to N=256 (wave tile
// 64px x 128ch, acc[4][8]). Phase 2 = q1 -> swizzled LDS. Phase 3 = G2 with
// A-frags from LDS and W2 direct from L2 (16-deep load batches, acc[2][16]).
__global__ __launch_bounds__(256, 2) void head_kernel(
    const float* __restrict__ X, const unsigned short* __restrict__ W1,
    const float* __restrict__ b1, const unsigned short* __restrict__ W2,
    const float* __restrict__ b2, unsigned short* __restrict__ q2out) {
  const int HW = 16384, K = 512;
  __shared__ __align__(16) char smem[65536];
  float* Af = (float*)smem;                              // [64][128] f32
  unsigned short* Bs = (unsigned short*)(smem + 32768);  // [256][64] bf16
  const int bid = blockIdx.x;            // 1024 = 8 b x 128 px-tiles
  const int b = bid >> 7, pt = bid & 127;
  const int p0 = pt * 128;
  const int tid = (int)threadIdx.x;
  const int w = tid >> 6, l = tid & 63;
  const int lr = l & 15, lg = l >> 4;
  const f32x4 zero = {0.f, 0.f, 0.f, 0.f};

  // ---- Phase 1: q1 = relu(x^T @ W1^T + b1), fused transpose, N=256 ----
  const int wm = (w >> 1) * 64;          // wave pixel base (0/64)
  const int wn = (w & 1) * 128;          // wave channel base (0/128)
  f32x4 acc[4][8];
#pragma unroll
  for (int m = 0; m < 4; m++)
#pragma unroll
    for (int n = 0; n < 8; n++) acc[m][n] = zero;
  {
    const float* Xb = X + (size_t)b * K * HW;
    const int arow = l >> 5, acol = l & 31;
    const int bsub = l >> 3, bcol = (l & 7) * 8;
#pragma unroll 1
    for (int kt = 0; kt < K; kt += 64) {
      __syncthreads();
#pragma unroll
      for (int i = 0; i < 8; i++) {      // A: x[kt+rk][p0..p0+128), swz source
        const int rk = w * 16 + i * 2 + arow;
        const int s = (rk >> 3) & 7;
        __builtin_amdgcn_global_load_lds(
            (AS1 void*)(Xb + (size_t)(kt + rk) * HW + p0 + ((acol ^ s) << 2)),
            (AS3 void*)(Af + (w * 16 + i * 2) * 128), 16, 0, 0);
      }
#pragma unroll
      for (int i = 0; i < 8; i++) {      // B: W1 rows w*64+i*8+bsub
        __builtin_amdgcn_global_load_lds(
            (AS1 void*)(W1 + (size_t)(w * 64 + i * 8 + bsub) * K + kt + bcol),
            (AS3 void*)(Bs + (w * 64 + i * 8) * 64), 16, 0, 0);
      }
      __syncthreads();
#pragma unroll
      for (int ks = 0; ks < 2; ks++) {
        const int s = ks * 4 + lg;
        bf16x8 aF[4];
#pragma unroll
        for (int m = 0; m < 4; m++) {
          const int p = wm + m * 16 + lr;
          const int cb = (((p >> 2) ^ s) << 2) | (p & 3);
          bf16x8 a;
#pragma unroll
          for (int j = 0; j < 8; j++)
            a[j] = (__bf16)Af[(ks * 32 + lg * 8 + j) * 128 + cb];
          aF[m] = a;
        }
#pragma unroll
        for (int n = 0; n < 8; n++) {
          bf16x8 bF = *(const bf16x8*)(Bs + (wn + n * 16 + lr) * 64 + ks * 32 + lg * 8);
#pragma unroll
          for (int m = 0; m < 4; m++) acc[m][n] = MFMA_16x16x32(aF[m], bF, acc[m][n]);
        }
      }
    }
  }
  __syncthreads();   // all waves done with Af/Bs MFMA reads
  // ---- Phase 2: q1 -> LDS (swizzled [128][256] bf16, aliases Af+Bs) ----
#pragma unroll
  for (int n = 0; n < 8; n++) {
    const int ch = wn + n * 16 + lr;
    const float bb = b1[ch];
#pragma unroll
    for (int m = 0; m < 4; m++)
#pragma unroll
      for (int r = 0; r < 4; r++) {
        const int px = wm + m * 16 + lg * 4 + r;
        const unsigned boff =
            ((unsigned)px * 512 + (unsigned)ch * 2) ^ (((unsigned)px & 7u) << 4);
        *(unsigned short*)(smem + boff) = f2bf(fmaxf(acc[m][n][r] + bb, 0.f));
      }
  }
  __syncthreads();
  // ---- Phase 3: q2 = relu(q1 @ W2^T + b2) -> global ----
  {
    const int pbase = w * 32;            // wave owns 32 pixel rows
    f32x4 acc2[2][16];
#pragma unroll
    for (int m = 0; m < 2; m++)
#pragma unroll
      for (int n = 0; n < 16; n++) acc2[m][n] = zero;
#pragma unroll
    for (int ks = 0; ks < 8; ks++) {
      bf16x8 aF[2];
#pragma unroll
      for (int m = 0; m < 2; m++) {
        const int p = pbase + m * 16 + lr;
        const unsigned boff = ((unsigned)p * 512 + (unsigned)(ks * 64 + lg * 16)) ^
                              (((unsigned)p & 7u) << 4);
        aF[m] = *(const bf16x8*)(smem + boff);
      }
#pragma unroll
      for (int n = 0; n < 16; n++) {
        bf16x8 bF = *(const bf16x8*)(W2 + (size_t)(n * 16 + lr) * 256 + ks * 32 + lg * 8);
        acc2[0][n] = MFMA_16x16x32(aF[0], bF, acc2[0][n]);
        acc2[1][n] = MFMA_16x16x32(aF[1], bF, acc2[1][n]);
      }
    }
    unsigned short* Cb = q2out + ((size_t)b * HW + p0 + pbase) * 256;
#pragma unroll
    for (int n = 0; n < 16; n++) {
      const int ch = n * 16 + lr;
      const float bb = b2[ch];
#pragma unroll
      for (int m = 0; m < 2; m++)
#pragma unroll
        for (int r = 0; r < 4; r++)
          Cb[(size_t)(m * 16 + lg * 4 + r) * 256 + ch] =
              f2bf(fmaxf(acc2[m][n][r] + bb, 0.f));
    }
  }
}

// ---------------- generic bf16 GEMM (G_up): C = relu(A @ Bt^T + bias) ----------------
// COLOC=2: 1D grid, m-quads sharing a B-tile co-located on one XCD.
template <int BIAS_ROW, int OUTF32, int COLOC>
__global__ __launch_bounds__(256, 4) void gemm_bt_relu(
    const unsigned short* __restrict__ A, const unsigned short* __restrict__ Bt,
    const float* __restrict__ bias, void* __restrict__ Cout,
    int M, int N, int K, long long sA, long long sB, long long sC) {
  __shared__ unsigned short As[128 * 64];
  __shared__ unsigned short Bs[128 * 64];
  int m0, n0, b;
  if (COLOC == 2) {            // M=512 (4 tiles), N=16384 (128 tiles), B=8
    const int g = blockIdx.x, x = g & 7, j = g >> 3;
    const int og = ((j >> 2) << 3) | x;
    m0 = (j & 3) * 128; n0 = (og & 127) * 128; b = og >> 7;
  } else {
    b = blockIdx.z; m0 = blockIdx.x * 128; n0 = blockIdx.y * 128;
  }
  const int tid = threadIdx.x;
  const int w = tid >> 6, l = tid & 63;
  const int lr = l & 15, lg = l >> 4;
  const int wm = (w >> 1) * 64, wn = (w & 1) * 64;
  const unsigned short* Ab = A + (size_t)b * sA + (size_t)m0 * K;
  const unsigned short* Btb = Bt + (size_t)b * sB + (size_t)n0 * K;
  const f32x4 zero = {0.f, 0.f, 0.f, 0.f};
  f32x4 acc[4][4];
#pragma unroll
  for (int m = 0; m < 4; m++)
#pragma unroll
    for (int n = 0; n < 4; n++) acc[m][n] = zero;

  const int srow = w * 32 + (l >> 3);
  const int scol = (l & 7) * 8;
  for (int kt = 0; kt < K; kt += 64) {
    __syncthreads();
#pragma unroll
    for (int i = 0; i < 4; i++) {
      __builtin_amdgcn_global_load_lds(
          (AS1 void*)(Ab + (size_t)(srow + i * 8) * K + kt + scol),
          (AS3 void*)(As + (w * 32 + i * 8) * 64), 16, 0, 0);
      __builtin_amdgcn_global_load_lds(
          (AS1 void*)(Btb + (size_t)(srow + i * 8) * K + kt + scol),
          (AS3 void*)(Bs + (w * 32 + i * 8) * 64), 16, 0, 0);
    }
    __syncthreads();
#pragma unroll
    for (int ks = 0; ks < 2; ks++) {
      bf16x8 aF[4], bF[4];
#pragma unroll
      for (int m = 0; m < 4; m++)
        aF[m] = *(const bf16x8*)(As + (wm + m * 16 + lr) * 64 + ks * 32 + lg * 8);
#pragma unroll
      for (int n = 0; n < 4; n++)
        bF[n] = *(const bf16x8*)(Bs + (wn + n * 16 + lr) * 64 + ks * 32 + lg * 8);
#pragma unroll
      for (int m = 0; m < 4; m++)
#pragma unroll
        for (int n = 0; n < 4; n++) acc[m][n] = MFMA_16x16x32(aF[m], bF[n], acc[m][n]);
    }
  }
#pragma unroll
  for (int m = 0; m < 4; m++) {
#pragma unroll
    for (int n = 0; n < 4; n++) {
      const int col = n0 + wn + n * 16 + lr;
      const float bc = BIAS_ROW ? 0.f : bias[col];
#pragma unroll
      for (int r = 0; r < 4; r++) {
        const int row = m0 + wm + m * 16 + lg * 4 + r;
        float v = acc[m][n][r] + (BIAS_ROW ? bias[row] : bc);
        v = fmaxf(v, 0.f);
        if (OUTF32)
          ((float*)Cout)[(size_t)b * sC + (size_t)row * N + col] = v;
        else
          ((unsigned short*)Cout)[(size_t)b * sC + (size_t)row * N + col] = f2bf(v);
      }
    }
  }
}

// ---------------- fused attention: ctxT = softmax(Q Kt^T /16) @ V ----------------
__global__ __launch_bounds__(256, 4) void attn_kernel(
    const unsigned short* __restrict__ Q, const unsigned short* __restrict__ Kt,
    const unsigned short* __restrict__ Vv, unsigned short* __restrict__ ctxT) {
  const int HW = 16384;
  __shared__ unsigned short Pls[128 * 160];
  const int b = blockIdx.y;
  const int pix0 = blockIdx.x * 128;
  const int tid = threadIdx.x;
  const int w = tid >> 6, l = tid & 63;
  const int lr = l & 15, lg = l >> 4;
  const unsigned short* Qb = Q + ((size_t)b * HW + pix0 + w * 32) * 256;
  const unsigned short* Kb = Kt + (size_t)b * 160 * 256;
  const unsigned short* Vb = Vv + (size_t)b * 256 * 160;
  const f32x4 zero = {0.f, 0.f, 0.f, 0.f};

  f32x4 acc[2][10];
#pragma unroll
  for (int m = 0; m < 2; m++)
#pragma unroll
    for (int n = 0; n < 10; n++) acc[m][n] = zero;
#pragma unroll 2
  for (int ks = 0; ks < 8; ks++) {
    bf16x8 aF[2];
#pragma unroll
    for (int m = 0; m < 2; m++)
      aF[m] = *(const bf16x8*)(Qb + (size_t)(m * 16 + lr) * 256 + ks * 32 + lg * 8);
#pragma unroll
    for (int n = 0; n < 10; n++) {
      bf16x8 bF = *(const bf16x8*)(Kb + (size_t)(n * 16 + lr) * 256 + ks * 32 + lg * 8);
      acc[0][n] = MFMA_16x16x32(aF[0], bF, acc[0][n]);
      acc[1][n] = MFMA_16x16x32(aF[1], bF, acc[1][n]);
    }
  }
  const float scale = 0.0625f;  // 1/sqrt(256)
#pragma unroll
  for (int m = 0; m < 2; m++) {
#pragma unroll
    for (int r = 0; r < 4; r++) {
      float lm = -1e30f;
#pragma unroll
      for (int n = 0; n < 10; n++) {
        float v = acc[m][n][r] * scale;
        acc[m][n][r] = v;
        if (n * 16 + lr < 150) lm = fmaxf(lm, v);
      }
#pragma unroll
      for (int msk = 1; msk <= 8; msk <<= 1) lm = fmaxf(lm, __shfl_xor(lm, msk, 64));
      float s = 0.f;
#pragma unroll
      for (int n = 0; n < 10; n++) {
        float p = (n * 16 + lr < 150) ? __expf(acc[m][n][r] - lm) : 0.f;
        acc[m][n][r] = p;
        s += p;
      }
#pragma unroll
      for (int msk = 1; msk <= 8; msk <<= 1) s += __shfl_xor(s, msk, 64);
      float inv = 1.f / s;
      const int row = w * 32 + m * 16 + lg * 4 + r;
      const unsigned sw = (unsigned)(row & 7) << 4;
#pragma unroll
      for (int n = 0; n < 10; n++) {
        unsigned boff = (unsigned)row * 320 + (unsigned)(n * 16 + lr) * 2;
        *(unsigned short*)((char*)Pls + (boff ^ sw)) = f2bf(acc[m][n][r] * inv);
      }
    }
  }
  __syncthreads();
  unsigned short* Cb = ctxT + ((size_t)b * HW + pix0 + w * 32) * 256;
#pragma unroll
  for (int half = 0; half < 2; half++) {
    f32x4 acc2[2][8];
#pragma unroll
    for (int m = 0; m < 2; m++)
#pragma unroll
      for (int n = 0; n < 8; n++) acc2[m][n] = zero;
    for (int ks = 0; ks < 5; ks++) {
      bf16x8 aP[2];
#pragma unroll
      for (int m = 0; m < 2; m++) {
        const int row = w * 32 + m * 16 + lr;
        unsigned boff = (unsigned)row * 320 + (unsigned)(ks * 64 + lg * 16);
        aP[m] = *(const bf16x8*)((const char*)Pls + (boff ^ ((unsigned)(row & 7) << 4)));
      }
#pragma unroll
      for (int n = 0; n < 8; n++) {
        const int ch = half * 128 + n * 16 + lr;
        bf16x8 bV = *(const bf16x8*)(Vb + (size_t)ch * 160 + ks * 32 + lg * 8);
        acc2[0][n] = MFMA_16x16x32(aP[0], bV, acc2[0][n]);
        acc2[1][n] = MFMA_16x16x32(aP[1], bV, acc2[1][n]);
      }
    }
#pragma unroll
    for (int m = 0; m < 2; m++)
#pragma unroll
      for (int n = 0; n < 8; n++)
#pragma unroll
        for (int r = 0; r < 4; r++)
          Cb[(size_t)(m * 16 + lg * 4 + r) * 256 + half * 128 + n * 16 + lr] =
              f2bf(acc2[m][n][r]);
  }
}

// ---------------- host launcher ----------------
extern "C" void kernel_launch(void* const* d_in, const int* in_sizes, int n_in,
                              void* d_out, int out_size, void* d_ws, size_t ws_size,
                              hipStream_t stream) {
  (void)in_sizes; (void)n_in; (void)out_size;
  const float* x     = (const float*)d_in[0];
  const float* proxy = (const float*)d_in[1];
  const float* w_fp1 = (const float*)d_in[2];
  const float* b_fp1 = (const float*)d_in[3];
  const float* w_fp2 = (const float*)d_in[4];
  const float* b_fp2 = (const float*)d_in[5];
  const float* w_fo1 = (const float*)d_in[6];
  const float* b_fo1 = (const float*)d_in[7];
  const float* w_fo2 = (const float*)d_in[8];
  const float* b_fo2 = (const float*)d_in[9];
  const float* w_fd  = (const float*)d_in[10];
  const float* b_fd  = (const float*)d_in[11];
  const float* w_fu  = (const float*)d_in[12];
  const float* b_fu  = (const float*)d_in[13];

  char* ws = (char*)d_ws;
  unsigned short* W1b  = (unsigned short*)(ws + 0);          // 256x512 bf16
  unsigned short* W2b  = (unsigned short*)(ws + 262144);     // 256x256
  unsigned short* Wub  = (unsigned short*)(ws + 393216);     // 512x256
  unsigned short* keyT = (unsigned short*)(ws + 655360);     // [8][160][256]
  unsigned short* Vv   = (unsigned short*)(ws + 1310720);    // [8][256][160]
  unsigned short* bufA = (unsigned short*)(ws + 2097152);    // q2 [8][16384][256]
  unsigned short* bufB = (unsigned short*)(ws + 2097152 + 67108864);  // ctxT
  if (ws_size < 2097152 + 2 * 67108864) return;

  dim3 blk(256);
  cast_weights<<<1280, blk, 0, stream>>>(w_fp1, w_fp2, w_fu, W1b, W2b, Wub);
  kv_kernel<<<dim3(20, 8), blk, 0, stream>>>(proxy, w_fo1, b_fo1, w_fo2, b_fo2,
                                             w_fd, b_fd, keyT, Vv);
  // q2 = head(x): gemm1(N=256) + G2 fused, q1 LDS-only
  head_kernel<<<1024, blk, 0, stream>>>(x, W1b, b_fp1, W2b, b_fp2, bufA);
  // ctxT = softmax(q2 keyT^T / 16) @ V -> bufB
  attn_kernel<<<dim3(128, 8), blk, 0, stream>>>(bufA, keyT, Vv, bufB);
  // out = relu(Wu @ ctxT^T + bu), fp32 channels-first  [r8 proven config]
  gemm_bt_relu<1, 1, 2><<<4096, blk, 0, stream>>>(
      Wub, bufB, b_fu, d_out, 512, 16384, 256,
      0, (long long)16384 * 256, (long long)512 * 16384);
}

// Round 11
// 368.463 us; speedup vs baseline: 1.2825x; 1.0648x over previous
//
#include <hip/hip_runtime.h>
#include <hip/hip_bf16.h>

// ObjectAttentionBlock on MI355X, round 11.
// r6/r7/r9/r10 restructures all lost to r8 (371.7us): short-K GEMM phases are
// occupancy/latency-bound and fusion trades away blocks/CU. This round: r8
// skeleton EXACTLY + two additive micro-opts: (1) weight casts merged into
// kv_kernel entry (one fewer launch), (2) K compile-time (KC=256) in
// gemm_bt_relu so the 4-step K-loop fully unrolls.

typedef __bf16 bf16x8 __attribute__((ext_vector_type(8)));
typedef float f32x4 __attribute__((ext_vector_type(4)));

#define AS1 __attribute__((address_space(1)))
#define AS3 __attribute__((address_space(3)))
#define MFMA_16x16x32(a, b, c) __builtin_amdgcn_mfma_f32_16x16x32_bf16((a), (b), (c), 0, 0, 0)

__device__ __forceinline__ unsigned short f2bf(float f) {
  union { float f; unsigned u; } x; x.f = f;
  unsigned r = (x.u + 0x7FFFu + ((x.u >> 16) & 1u)) >> 16;  // RNE
  return (unsigned short)r;
}

// ---------------- key/value kernel + merged weight casts ----------------
__global__ __launch_bounds__(256) void kv_kernel(
    const float* __restrict__ proxy,
    const float* __restrict__ w_fo1, const float* __restrict__ b_fo1,
    const float* __restrict__ w_fo2, const float* __restrict__ b_fo2,
    const float* __restrict__ w_fd, const float* __restrict__ b_fd,
    unsigned short* __restrict__ keyT, unsigned short* __restrict__ Vv,
    const float* __restrict__ w1, const float* __restrict__ w2,
    const float* __restrict__ wu, unsigned short* __restrict__ W1b,
    unsigned short* __restrict__ W2b, unsigned short* __restrict__ Wub) {
  __shared__ float cols[512][8];
  __shared__ float k1s[256][8];
  const int b = blockIdx.y;
  const int p0 = blockIdx.x * 8;      // 20 chunks cover p 0..159
  const int t = threadIdx.x;
  // ---- merged weight casts: 160 blocks x 256 thr x 8 = 327680 items exact
  {
    const int base = ((b * 20 + blockIdx.x) * 256 + t) * 8;
#pragma unroll
    for (int i = 0; i < 8; i++) {
      const int idx = base + i;
      if (idx < 131072) W1b[idx] = f2bf(w1[idx]);
      else if (idx < 196608) W2b[idx - 131072] = f2bf(w2[idx - 131072]);
      else Wub[idx - 196608] = f2bf(wu[idx - 196608]);
    }
  }
#pragma unroll
  for (int i = 0; i < 8; i++) {
    int idx = t + i * 256;
    int c = idx >> 2, q = idx & 3;
    int p = p0 + q * 2;
    float2 v = make_float2(0.f, 0.f);
    if (p < 150) v = *(const float2*)(proxy + ((size_t)b * 512 + c) * 150 + p);
    cols[c][q * 2 + 0] = v.x;
    cols[c][q * 2 + 1] = v.y;
  }
  __syncthreads();
  float accV[8], accK[8];
  {
    float bv = b_fd[t], bk = b_fo1[t];
#pragma unroll
    for (int px = 0; px < 8; px++) { accV[px] = bv; accK[px] = bk; }
  }
#define KV_FMA(j, wv_, wk_)                                      \
  { float4 ca = *(const float4*)&cols[c + j][0];                 \
    float4 cb = *(const float4*)&cols[c + j][4];                 \
    accV[0] += wv_ * ca.x; accV[1] += wv_ * ca.y;                \
    accV[2] += wv_ * ca.z; accV[3] += wv_ * ca.w;                \
    accV[4] += wv_ * cb.x; accV[5] += wv_ * cb.y;                \
    accV[6] += wv_ * cb.z; accV[7] += wv_ * cb.w;                \
    accK[0] += wk_ * ca.x; accK[1] += wk_ * ca.y;                \
    accK[2] += wk_ * ca.z; accK[3] += wk_ * ca.w;                \
    accK[4] += wk_ * cb.x; accK[5] += wk_ * cb.y;                \
    accK[6] += wk_ * cb.z; accK[7] += wk_ * cb.w; }
  for (int c = 0; c < 512; c += 4) {
    float4 wv4 = *(const float4*)(w_fd + (size_t)t * 512 + c);
    float4 wk4 = *(const float4*)(w_fo1 + (size_t)t * 512 + c);
    KV_FMA(0, wv4.x, wk4.x)
    KV_FMA(1, wv4.y, wk4.y)
    KV_FMA(2, wv4.z, wk4.z)
    KV_FMA(3, wv4.w, wk4.w)
  }
#pragma unroll
  for (int px = 0; px < 8; px++) {
    Vv[((size_t)b * 256 + t) * 160 + p0 + px] = f2bf(fmaxf(accV[px], 0.f));
    k1s[t][px] = fmaxf(accK[px], 0.f);
  }
  __syncthreads();
  float accY[8];
  {
    float by = b_fo2[t];
#pragma unroll
    for (int px = 0; px < 8; px++) accY[px] = by;
  }
#define KV_FMA2(j, wy_)                                          \
  { float4 ca = *(const float4*)&k1s[c + j][0];                  \
    float4 cb = *(const float4*)&k1s[c + j][4];                  \
    accY[0] += wy_ * ca.x; accY[1] += wy_ * ca.y;                \
    accY[2] += wy_ * ca.z; accY[3] += wy_ * ca.w;                \
    accY[4] += wy_ * cb.x; accY[5] += wy_ * cb.y;                \
    accY[6] += wy_ * cb.z; accY[7] += wy_ * cb.w; }
  for (int c = 0; c < 256; c += 4) {
    float4 wy4 = *(const float4*)(w_fo2 + (size_t)t * 256 + c);
    KV_FMA2(0, wy4.x)
    KV_FMA2(1, wy4.y)
    KV_FMA2(2, wy4.z)
    KV_FMA2(3, wy4.w)
  }
#pragma unroll
  for (int px = 0; px < 8; px++)
    keyT[((size_t)b * 160 + p0 + px) * 256 + t] = f2bf(fmaxf(accY[px], 0.f));
}

// ---------------- GEMM1 fused transpose: q1T = relu(x^T @ W1^T + b1) ----------------
__global__ __launch_bounds__(256, 3) void gemm1_fused(
    const float* __restrict__ X, const unsigned short* __restrict__ Bt,
    const float* __restrict__ bias, unsigned short* __restrict__ Cq) {
  const int HW = 16384, K = 512, N = 256;
  __shared__ float Af[64 * 128];
  __shared__ unsigned short Bs[128 * 64];
  const int r = blockIdx.x;                 // 0..255
  const int b = blockIdx.y;
  const int my = ((r >> 4) << 3) | (r & 7); // 0..127
  const int nx = (r >> 3) & 1;
  const int m0 = my * 128, n0 = nx * 128;
  const int tid = threadIdx.x;
  const int w = tid >> 6, l = tid & 63;
  const int lr = l & 15, lg = l >> 4;
  const int wm = (w >> 1) * 64, wn = (w & 1) * 64;
  const float* Xb = X + (size_t)b * K * HW;
  const unsigned short* Btb = Bt + (size_t)n0 * K;
  const f32x4 zero = {0.f, 0.f, 0.f, 0.f};
  f32x4 acc[4][4];
#pragma unroll
  for (int m = 0; m < 4; m++)
#pragma unroll
    for (int n = 0; n < 4; n++) acc[m][n] = zero;

  const int arow = l >> 5, acol = l & 31;
  const int bsub = l >> 3, bcol = (l & 7) * 8;
  for (int kt = 0; kt < K; kt += 64) {
    __syncthreads();
#pragma unroll
    for (int i = 0; i < 8; i++) {
      const int rk = w * 16 + i * 2 + arow;
      const int s = (rk >> 3) & 7;
      __builtin_amdgcn_global_load_lds(
          (AS1 void*)(Xb + (size_t)(kt + rk) * HW + m0 + ((acol ^ s) << 2)),
          (AS3 void*)(Af + (w * 16 + i * 2) * 128), 16, 0, 0);
    }
#pragma unroll
    for (int i = 0; i < 4; i++) {
      __builtin_amdgcn_global_load_lds(
          (AS1 void*)(Btb + (size_t)(w * 32 + i * 8 + bsub) * K + kt + bcol),
          (AS3 void*)(Bs + (w * 32 + i * 8) * 64), 16, 0, 0);
    }
    __syncthreads();
#pragma unroll
    for (int ks = 0; ks < 2; ks++) {
      bf16x8 aF[4], bF[4];
      const int s = ks * 4 + lg;
#pragma unroll
      for (int m = 0; m < 4; m++) {
        const int p = wm + m * 16 + lr;
        const int cb = ((((p >> 2) ^ s) << 2) | (p & 3));
        bf16x8 a;
#pragma unroll
        for (int j = 0; j < 8; j++)
          a[j] = (__bf16)Af[(ks * 32 + lg * 8 + j) * 128 + cb];
        aF[m] = a;
      }
#pragma unroll
      for (int n = 0; n < 4; n++)
        bF[n] = *(const bf16x8*)(Bs + (wn + n * 16 + lr) * 64 + ks * 32 + lg * 8);
#pragma unroll
      for (int m = 0; m < 4; m++)
#pragma unroll
        for (int n = 0; n < 4; n++) acc[m][n] = MFMA_16x16x32(aF[m], bF[n], acc[m][n]);
    }
  }
  unsigned short* Cb = Cq + (size_t)b * HW * N;
#pragma unroll
  for (int m = 0; m < 4; m++) {
#pragma unroll
    for (int n = 0; n < 4; n++) {
      const int col = n0 + wn + n * 16 + lr;
      const float bc = bias[col];
#pragma unroll
      for (int r2 = 0; r2 < 4; r2++) {
        const int row = m0 + wm + m * 16 + lg * 4 + r2;
        Cb[(size_t)row * N + col] = f2bf(fmaxf(acc[m][n][r2] + bc, 0.f));
      }
    }
  }
}

// ---------------- generic bf16 GEMM: C = relu(A @ Bt^T + bias), K=KC ----------------
// COLOC=1 (G2): n-pairs sharing an A-tile co-located per XCD. COLOC=2 (G_up):
// m-quads sharing a B-tile co-located. KC compile-time -> full K-loop unroll.
template <int BIAS_ROW, int OUTF32, int COLOC, int KC>
__global__ __launch_bounds__(256, 4) void gemm_bt_relu(
    const unsigned short* __restrict__ A, const unsigned short* __restrict__ Bt,
    const float* __restrict__ bias, void* __restrict__ Cout,
    int M, int N, long long sA, long long sB, long long sC) {
  __shared__ unsigned short As[128 * 64];
  __shared__ unsigned short Bs[128 * 64];
  int m0, n0, b;
  if (COLOC == 1) {            // M=16384 (128 tiles), N=256 (2 tiles), B=8
    const int g = blockIdx.x, x = g & 7, j = g >> 3;
    const int og = ((j >> 1) << 3) | x;      // (pix,b) id, 0..1023
    n0 = (j & 1) * 128; m0 = (og & 127) * 128; b = og >> 7;
  } else if (COLOC == 2) {     // M=512 (4 tiles), N=16384 (128 tiles), B=8
    const int g = blockIdx.x, x = g & 7, j = g >> 3;
    const int og = ((j >> 2) << 3) | x;
    m0 = (j & 3) * 128; n0 = (og & 127) * 128; b = og >> 7;
  } else {
    b = blockIdx.z; m0 = blockIdx.x * 128; n0 = blockIdx.y * 128;
  }
  const int tid = threadIdx.x;
  const int w = tid >> 6, l = tid & 63;
  const int lr = l & 15, lg = l >> 4;
  const int wm = (w >> 1) * 64, wn = (w & 1) * 64;
  const unsigned short* Ab = A + (size_t)b * sA + (size_t)m0 * KC;
  const unsigned short* Btb = Bt + (size_t)b * sB + (size_t)n0 * KC;
  const f32x4 zero = {0.f, 0.f, 0.f, 0.f};
  f32x4 acc[4][4];
#pragma unroll
  for (int m = 0; m < 4; m++)
#pragma unroll
    for (int n = 0; n < 4; n++) acc[m][n] = zero;

  const int srow = w * 32 + (l >> 3);
  const int scol = (l & 7) * 8;
#pragma unroll
  for (int kt = 0; kt < KC; kt += 64) {
    __syncthreads();
#pragma unroll
    for (int i = 0; i < 4; i++) {
      __builtin_amdgcn_global_load_lds(
          (AS1 void*)(Ab + (size_t)(srow + i * 8) * KC + kt + scol),
          (AS3 void*)(As + (w * 32 + i * 8) * 64), 16, 0, 0);
      __builtin_amdgcn_global_load_lds(
          (AS1 void*)(Btb + (size_t)(srow + i * 8) * KC + kt + scol),
          (AS3 void*)(Bs + (w * 32 + i * 8) * 64), 16, 0, 0);
    }
    __syncthreads();
#pragma unroll
    for (int ks = 0; ks < 2; ks++) {
      bf16x8 aF[4], bF[4];
#pragma unroll
      for (int m = 0; m < 4; m++)
        aF[m] = *(const bf16x8*)(As + (wm + m * 16 + lr) * 64 + ks * 32 + lg * 8);
#pragma unroll
      for (int n = 0; n < 4; n++)
        bF[n] = *(const bf16x8*)(Bs + (wn + n * 16 + lr) * 64 + ks * 32 + lg * 8);
#pragma unroll
      for (int m = 0; m < 4; m++)
#pragma unroll
        for (int n = 0; n < 4; n++) acc[m][n] = MFMA_16x16x32(aF[m], bF[n], acc[m][n]);
    }
  }
#pragma unroll
  for (int m = 0; m < 4; m++) {
#pragma unroll
    for (int n = 0; n < 4; n++) {
      const int col = n0 + wn + n * 16 + lr;
      const float bc = BIAS_ROW ? 0.f : bias[col];
#pragma unroll
      for (int r = 0; r < 4; r++) {
        const int row = m0 + wm + m * 16 + lg * 4 + r;
        float v = acc[m][n][r] + (BIAS_ROW ? bias[row] : bc);
        v = fmaxf(v, 0.f);
        if (OUTF32)
          ((float*)Cout)[(size_t)b * sC + (size_t)row * N + col] = v;
        else
          ((unsigned short*)Cout)[(size_t)b * sC + (size_t)row * N + col] = f2bf(v);
      }
    }
  }
}

// ---------------- fused attention: ctxT = softmax(Q Kt^T /16) @ V ----------------
__global__ __launch_bounds__(256, 4) void attn_kernel(
    const unsigned short* __restrict__ Q, const unsigned short* __restrict__ Kt,
    const unsigned short* __restrict__ Vv, unsigned short* __restrict__ ctxT) {
  const int HW = 16384;
  __shared__ unsigned short Pls[128 * 160];
  const int b = blockIdx.y;
  const int pix0 = blockIdx.x * 128;
  const int tid = threadIdx.x;
  const int w = tid >> 6, l = tid & 63;
  const int lr = l & 15, lg = l >> 4;
  const unsigned short* Qb = Q + ((size_t)b * HW + pix0 + w * 32) * 256;
  const unsigned short* Kb = Kt + (size_t)b * 160 * 256;
  const unsigned short* Vb = Vv + (size_t)b * 256 * 160;
  const f32x4 zero = {0.f, 0.f, 0.f, 0.f};

  f32x4 acc[2][10];
#pragma unroll
  for (int m = 0; m < 2; m++)
#pragma unroll
    for (int n = 0; n < 10; n++) acc[m][n] = zero;
#pragma unroll 2
  for (int ks = 0; ks < 8; ks++) {
    bf16x8 aF[2];
#pragma unroll
    for (int m = 0; m < 2; m++)
      aF[m] = *(const bf16x8*)(Qb + (size_t)(m * 16 + lr) * 256 + ks * 32 + lg * 8);
#pragma unroll
    for (int n = 0; n < 10; n++) {
      bf16x8 bF = *(const bf16x8*)(Kb + (size_t)(n * 16 + lr) * 256 + ks * 32 + lg * 8);
      acc[0][n] = MFMA_16x16x32(aF[0], bF, acc[0][n]);
      acc[1][n] = MFMA_16x16x32(aF[1], bF, acc[1][n]);
    }
  }
  const float scale = 0.0625f;  // 1/sqrt(256)
#pragma unroll
  for (int m = 0; m < 2; m++) {
#pragma unroll
    for (int r = 0; r < 4; r++) {
      float lm = -1e30f;
#pragma unroll
      for (int n = 0; n < 10; n++) {
        float v = acc[m][n][r] * scale;
        acc[m][n][r] = v;
        if (n * 16 + lr < 150) lm = fmaxf(lm, v);
      }
#pragma unroll
      for (int msk = 1; msk <= 8; msk <<= 1) lm = fmaxf(lm, __shfl_xor(lm, msk, 64));
      float s = 0.f;
#pragma unroll
      for (int n = 0; n < 10; n++) {
        float p = (n * 16 + lr < 150) ? __expf(acc[m][n][r] - lm) : 0.f;
        acc[m][n][r] = p;
        s += p;
      }
#pragma unroll
      for (int msk = 1; msk <= 8; msk <<= 1) s += __shfl_xor(s, msk, 64);
      float inv = 1.f / s;
      const int row = w * 32 + m * 16 + lg * 4 + r;
      const unsigned sw = (unsigned)(row & 7) << 4;
#pragma unroll
      for (int n = 0; n < 10; n++) {
        unsigned boff = (unsigned)row * 320 + (unsigned)(n * 16 + lr) * 2;
        *(unsigned short*)((char*)Pls + (boff ^ sw)) = f2bf(acc[m][n][r] * inv);
      }
    }
  }
  __syncthreads();
  unsigned short* Cb = ctxT + ((size_t)b * HW + pix0 + w * 32) * 256;
#pragma unroll
  for (int half = 0; half < 2; half++) {
    f32x4 acc2[2][8];
#pragma unroll
    for (int m = 0; m < 2; m++)
#pragma unroll
      for (int n = 0; n < 8; n++) acc2[m][n] = zero;
    for (int ks = 0; ks < 5; ks++) {
      bf16x8 aP[2];
#pragma unroll
      for (int m = 0; m < 2; m++) {
        const int row = w * 32 + m * 16 + lr;
        unsigned boff = (unsigned)row * 320 + (unsigned)(ks * 64 + lg * 16);
        aP[m] = *(const bf16x8*)((const char*)Pls + (boff ^ ((unsigned)(row & 7) << 4)));
      }
#pragma unroll
      for (int n = 0; n < 8; n++) {
        const int ch = half * 128 + n * 16 + lr;
        bf16x8 bV = *(const bf16x8*)(Vb + (size_t)ch * 160 + ks * 32 + lg * 8);
        acc2[0][n] = MFMA_16x16x32(aP[0], bV, acc2[0][n]);
        acc2[1][n] = MFMA_16x16x32(aP[1], bV, acc2[1][n]);
      }
    }
#pragma unroll
    for (int m = 0; m < 2; m++)
#pragma unroll
      for (int n = 0; n < 8; n++)
#pragma unroll
        for (int r = 0; r < 4; r++)
          Cb[(size_t)(m * 16 + lg * 4 + r) * 256 + half * 128 + n * 16 + lr] =
              f2bf(acc2[m][n][r]);
  }
}

// ---------------- host launcher ----------------
extern "C" void kernel_launch(void* const* d_in, const int* in_sizes, int n_in,
                              void* d_out, int out_size, void* d_ws, size_t ws_size,
                              hipStream_t stream) {
  (void)in_sizes; (void)n_in; (void)out_size;
  const float* x     = (const float*)d_in[0];
  const float* proxy = (const float*)d_in[1];
  const float* w_fp1 = (const float*)d_in[2];
  const float* b_fp1 = (const float*)d_in[3];
  const float* w_fp2 = (const float*)d_in[4];
  const float* b_fp2 = (const float*)d_in[5];
  const float* w_fo1 = (const float*)d_in[6];
  const float* b_fo1 = (const float*)d_in[7];
  const float* w_fo2 = (const float*)d_in[8];
  const float* b_fo2 = (const float*)d_in[9];
  const float* w_fd  = (const float*)d_in[10];
  const float* b_fd  = (const float*)d_in[11];
  const float* w_fu  = (const float*)d_in[12];
  const float* b_fu  = (const float*)d_in[13];

  char* ws = (char*)d_ws;
  unsigned short* W1b  = (unsigned short*)(ws + 0);          // 256x512 bf16
  unsigned short* W2b  = (unsigned short*)(ws + 262144);     // 256x256
  unsigned short* Wub  = (unsigned short*)(ws + 393216);     // 512x256
  unsigned short* keyT = (unsigned short*)(ws + 655360);     // [8][160][256]
  unsigned short* Vv   = (unsigned short*)(ws + 1310720);    // [8][256][160]
  unsigned short* bufA = (unsigned short*)(ws + 2097152);    // q2T
  unsigned short* bufB = (unsigned short*)(ws + 2097152 + 134217728);  // q1T, later ctxT
  if (ws_size < 203423744) return;

  dim3 blk(256);
  // kv + merged weight casts (stream order guarantees W*b ready for gemms)
  kv_kernel<<<dim3(20, 8), blk, 0, stream>>>(proxy, w_fo1, b_fo1, w_fo2, b_fo2,
                                             w_fd, b_fd, keyT, Vv,
                                             w_fp1, w_fp2, w_fu, W1b, W2b, Wub);
  // q1 = relu(x^T @ W1^T + b1) with fused transpose -> bufB
  gemm1_fused<<<dim3(256, 8), blk, 0, stream>>>(x, W1b, b_fp1, bufB);
  // q2 = relu(q1 @ W2^T + b2) -> bufA   [XCD co-located n-pairs, KC=256]
  gemm_bt_relu<0, 0, 1, 256><<<2048, blk, 0, stream>>>(
      bufB, W2b, b_fp2, bufA, 16384, 256,
      (long long)16384 * 256, 0, (long long)16384 * 256);
  // ctxT = softmax(q2 keyT^T / 16) @ V -> bufB
  attn_kernel<<<dim3(128, 8), blk, 0, stream>>>(bufA, keyT, Vv, bufB);
  // out = relu(Wu @ ctxT^T + bu), fp32 channels-first  [XCD co-located m-quads]
  gemm_bt_relu<1, 1, 2, 256><<<4096, blk, 0, stream>>>(
      Wub, bufB, b_fu, d_out, 512, 16384,
      0, (long long)16384 * 256, (long long)512 * 16384);
}

// Round 12
// 360.452 us; speedup vs baseline: 1.3110x; 1.0222x over previous
//
#include <hip/hip_runtime.h>
#include <hip/hip_bf16.h>

// ObjectAttentionBlock on MI355X, round 12.
// r11 = 368.5us best. This round, attn-only scheduling change: the softmax->PV
// __syncthreads is removed (P rows are wave-private: wave w writes AND reads
// only rows w*32..w*32+31; same-wave LDS ordering guaranteed by lgkmcnt) and
// s_setprio(1) wraps the MFMA clusters (T5 pays once waves phase-diverge).

typedef __bf16 bf16x8 __attribute__((ext_vector_type(8)));
typedef float f32x4 __attribute__((ext_vector_type(4)));

#define AS1 __attribute__((address_space(1)))
#define AS3 __attribute__((address_space(3)))
#define MFMA_16x16x32(a, b, c) __builtin_amdgcn_mfma_f32_16x16x32_bf16((a), (b), (c), 0, 0, 0)

__device__ __forceinline__ unsigned short f2bf(float f) {
  union { float f; unsigned u; } x; x.f = f;
  unsigned r = (x.u + 0x7FFFu + ((x.u >> 16) & 1u)) >> 16;  // RNE
  return (unsigned short)r;
}

// ---------------- key/value kernel + merged weight casts ----------------
__global__ __launch_bounds__(256) void kv_kernel(
    const float* __restrict__ proxy,
    const float* __restrict__ w_fo1, const float* __restrict__ b_fo1,
    const float* __restrict__ w_fo2, const float* __restrict__ b_fo2,
    const float* __restrict__ w_fd, const float* __restrict__ b_fd,
    unsigned short* __restrict__ keyT, unsigned short* __restrict__ Vv,
    const float* __restrict__ w1, const float* __restrict__ w2,
    const float* __restrict__ wu, unsigned short* __restrict__ W1b,
    unsigned short* __restrict__ W2b, unsigned short* __restrict__ Wub) {
  __shared__ float cols[512][8];
  __shared__ float k1s[256][8];
  const int b = blockIdx.y;
  const int p0 = blockIdx.x * 8;      // 20 chunks cover p 0..159
  const int t = threadIdx.x;
  // ---- merged weight casts: 160 blocks x 256 thr x 8 = 327680 items exact
  {
    const int base = ((b * 20 + blockIdx.x) * 256 + t) * 8;
#pragma unroll
    for (int i = 0; i < 8; i++) {
      const int idx = base + i;
      if (idx < 131072) W1b[idx] = f2bf(w1[idx]);
      else if (idx < 196608) W2b[idx - 131072] = f2bf(w2[idx - 131072]);
      else Wub[idx - 196608] = f2bf(wu[idx - 196608]);
    }
  }
#pragma unroll
  for (int i = 0; i < 8; i++) {
    int idx = t + i * 256;
    int c = idx >> 2, q = idx & 3;
    int p = p0 + q * 2;
    float2 v = make_float2(0.f, 0.f);
    if (p < 150) v = *(const float2*)(proxy + ((size_t)b * 512 + c) * 150 + p);
    cols[c][q * 2 + 0] = v.x;
    cols[c][q * 2 + 1] = v.y;
  }
  __syncthreads();
  float accV[8], accK[8];
  {
    float bv = b_fd[t], bk = b_fo1[t];
#pragma unroll
    for (int px = 0; px < 8; px++) { accV[px] = bv; accK[px] = bk; }
  }
#define KV_FMA(j, wv_, wk_)                                      \
  { float4 ca = *(const float4*)&cols[c + j][0];                 \
    float4 cb = *(const float4*)&cols[c + j][4];                 \
    accV[0] += wv_ * ca.x; accV[1] += wv_ * ca.y;                \
    accV[2] += wv_ * ca.z; accV[3] += wv_ * ca.w;                \
    accV[4] += wv_ * cb.x; accV[5] += wv_ * cb.y;                \
    accV[6] += wv_ * cb.z; accV[7] += wv_ * cb.w;                \
    accK[0] += wk_ * ca.x; accK[1] += wk_ * ca.y;                \
    accK[2] += wk_ * ca.z; accK[3] += wk_ * ca.w;                \
    accK[4] += wk_ * cb.x; accK[5] += wk_ * cb.y;                \
    accK[6] += wk_ * cb.z; accK[7] += wk_ * cb.w; }
  for (int c = 0; c < 512; c += 4) {
    float4 wv4 = *(const float4*)(w_fd + (size_t)t * 512 + c);
    float4 wk4 = *(const float4*)(w_fo1 + (size_t)t * 512 + c);
    KV_FMA(0, wv4.x, wk4.x)
    KV_FMA(1, wv4.y, wk4.y)
    KV_FMA(2, wv4.z, wk4.z)
    KV_FMA(3, wv4.w, wk4.w)
  }
#pragma unroll
  for (int px = 0; px < 8; px++) {
    Vv[((size_t)b * 256 + t) * 160 + p0 + px] = f2bf(fmaxf(accV[px], 0.f));
    k1s[t][px] = fmaxf(accK[px], 0.f);
  }
  __syncthreads();
  float accY[8];
  {
    float by = b_fo2[t];
#pragma unroll
    for (int px = 0; px < 8; px++) accY[px] = by;
  }
#define KV_FMA2(j, wy_)                                          \
  { float4 ca = *(const float4*)&k1s[c + j][0];                  \
    float4 cb = *(const float4*)&k1s[c + j][4];                  \
    accY[0] += wy_ * ca.x; accY[1] += wy_ * ca.y;                \
    accY[2] += wy_ * ca.z; accY[3] += wy_ * ca.w;                \
    accY[4] += wy_ * cb.x; accY[5] += wy_ * cb.y;                \
    accY[6] += wy_ * cb.z; accY[7] += wy_ * cb.w; }
  for (int c = 0; c < 256; c += 4) {
    float4 wy4 = *(const float4*)(w_fo2 + (size_t)t * 256 + c);
    KV_FMA2(0, wy4.x)
    KV_FMA2(1, wy4.y)
    KV_FMA2(2, wy4.z)
    KV_FMA2(3, wy4.w)
  }
#pragma unroll
  for (int px = 0; px < 8; px++)
    keyT[((size_t)b * 160 + p0 + px) * 256 + t] = f2bf(fmaxf(accY[px], 0.f));
}

// ---------------- GEMM1 fused transpose: q1T = relu(x^T @ W1^T + b1) ----------------
__global__ __launch_bounds__(256, 3) void gemm1_fused(
    const float* __restrict__ X, const unsigned short* __restrict__ Bt,
    const float* __restrict__ bias, unsigned short* __restrict__ Cq) {
  const int HW = 16384, K = 512, N = 256;
  __shared__ float Af[64 * 128];
  __shared__ unsigned short Bs[128 * 64];
  const int r = blockIdx.x;                 // 0..255
  const int b = blockIdx.y;
  const int my = ((r >> 4) << 3) | (r & 7); // 0..127
  const int nx = (r >> 3) & 1;
  const int m0 = my * 128, n0 = nx * 128;
  const int tid = threadIdx.x;
  const int w = tid >> 6, l = tid & 63;
  const int lr = l & 15, lg = l >> 4;
  const int wm = (w >> 1) * 64, wn = (w & 1) * 64;
  const float* Xb = X + (size_t)b * K * HW;
  const unsigned short* Btb = Bt + (size_t)n0 * K;
  const f32x4 zero = {0.f, 0.f, 0.f, 0.f};
  f32x4 acc[4][4];
#pragma unroll
  for (int m = 0; m < 4; m++)
#pragma unroll
    for (int n = 0; n < 4; n++) acc[m][n] = zero;

  const int arow = l >> 5, acol = l & 31;
  const int bsub = l >> 3, bcol = (l & 7) * 8;
  for (int kt = 0; kt < K; kt += 64) {
    __syncthreads();
#pragma unroll
    for (int i = 0; i < 8; i++) {
      const int rk = w * 16 + i * 2 + arow;
      const int s = (rk >> 3) & 7;
      __builtin_amdgcn_global_load_lds(
          (AS1 void*)(Xb + (size_t)(kt + rk) * HW + m0 + ((acol ^ s) << 2)),
          (AS3 void*)(Af + (w * 16 + i * 2) * 128), 16, 0, 0);
    }
#pragma unroll
    for (int i = 0; i < 4; i++) {
      __builtin_amdgcn_global_load_lds(
          (AS1 void*)(Btb + (size_t)(w * 32 + i * 8 + bsub) * K + kt + bcol),
          (AS3 void*)(Bs + (w * 32 + i * 8) * 64), 16, 0, 0);
    }
    __syncthreads();
#pragma unroll
    for (int ks = 0; ks < 2; ks++) {
      bf16x8 aF[4], bF[4];
      const int s = ks * 4 + lg;
#pragma unroll
      for (int m = 0; m < 4; m++) {
        const int p = wm + m * 16 + lr;
        const int cb = ((((p >> 2) ^ s) << 2) | (p & 3));
        bf16x8 a;
#pragma unroll
        for (int j = 0; j < 8; j++)
          a[j] = (__bf16)Af[(ks * 32 + lg * 8 + j) * 128 + cb];
        aF[m] = a;
      }
#pragma unroll
      for (int n = 0; n < 4; n++)
        bF[n] = *(const bf16x8*)(Bs + (wn + n * 16 + lr) * 64 + ks * 32 + lg * 8);
#pragma unroll
      for (int m = 0; m < 4; m++)
#pragma unroll
        for (int n = 0; n < 4; n++) acc[m][n] = MFMA_16x16x32(aF[m], bF[n], acc[m][n]);
    }
  }
  unsigned short* Cb = Cq + (size_t)b * HW * N;
#pragma unroll
  for (int m = 0; m < 4; m++) {
#pragma unroll
    for (int n = 0; n < 4; n++) {
      const int col = n0 + wn + n * 16 + lr;
      const float bc = bias[col];
#pragma unroll
      for (int r2 = 0; r2 < 4; r2++) {
        const int row = m0 + wm + m * 16 + lg * 4 + r2;
        Cb[(size_t)row * N + col] = f2bf(fmaxf(acc[m][n][r2] + bc, 0.f));
      }
    }
  }
}

// ---------------- generic bf16 GEMM: C = relu(A @ Bt^T + bias), K=KC ----------------
template <int BIAS_ROW, int OUTF32, int COLOC, int KC>
__global__ __launch_bounds__(256, 4) void gemm_bt_relu(
    const unsigned short* __restrict__ A, const unsigned short* __restrict__ Bt,
    const float* __restrict__ bias, void* __restrict__ Cout,
    int M, int N, long long sA, long long sB, long long sC) {
  __shared__ unsigned short As[128 * 64];
  __shared__ unsigned short Bs[128 * 64];
  int m0, n0, b;
  if (COLOC == 1) {            // M=16384 (128 tiles), N=256 (2 tiles), B=8
    const int g = blockIdx.x, x = g & 7, j = g >> 3;
    const int og = ((j >> 1) << 3) | x;      // (pix,b) id, 0..1023
    n0 = (j & 1) * 128; m0 = (og & 127) * 128; b = og >> 7;
  } else if (COLOC == 2) {     // M=512 (4 tiles), N=16384 (128 tiles), B=8
    const int g = blockIdx.x, x = g & 7, j = g >> 3;
    const int og = ((j >> 2) << 3) | x;
    m0 = (j & 3) * 128; n0 = (og & 127) * 128; b = og >> 7;
  } else {
    b = blockIdx.z; m0 = blockIdx.x * 128; n0 = blockIdx.y * 128;
  }
  const int tid = threadIdx.x;
  const int w = tid >> 6, l = tid & 63;
  const int lr = l & 15, lg = l >> 4;
  const int wm = (w >> 1) * 64, wn = (w & 1) * 64;
  const unsigned short* Ab = A + (size_t)b * sA + (size_t)m0 * KC;
  const unsigned short* Btb = Bt + (size_t)b * sB + (size_t)n0 * KC;
  const f32x4 zero = {0.f, 0.f, 0.f, 0.f};
  f32x4 acc[4][4];
#pragma unroll
  for (int m = 0; m < 4; m++)
#pragma unroll
    for (int n = 0; n < 4; n++) acc[m][n] = zero;

  const int srow = w * 32 + (l >> 3);
  const int scol = (l & 7) * 8;
#pragma unroll
  for (int kt = 0; kt < KC; kt += 64) {
    __syncthreads();
#pragma unroll
    for (int i = 0; i < 4; i++) {
      __builtin_amdgcn_global_load_lds(
          (AS1 void*)(Ab + (size_t)(srow + i * 8) * KC + kt + scol),
          (AS3 void*)(As + (w * 32 + i * 8) * 64), 16, 0, 0);
      __builtin_amdgcn_global_load_lds(
          (AS1 void*)(Btb + (size_t)(srow + i * 8) * KC + kt + scol),
          (AS3 void*)(Bs + (w * 32 + i * 8) * 64), 16, 0, 0);
    }
    __syncthreads();
#pragma unroll
    for (int ks = 0; ks < 2; ks++) {
      bf16x8 aF[4], bF[4];
#pragma unroll
      for (int m = 0; m < 4; m++)
        aF[m] = *(const bf16x8*)(As + (wm + m * 16 + lr) * 64 + ks * 32 + lg * 8);
#pragma unroll
      for (int n = 0; n < 4; n++)
        bF[n] = *(const bf16x8*)(Bs + (wn + n * 16 + lr) * 64 + ks * 32 + lg * 8);
#pragma unroll
      for (int m = 0; m < 4; m++)
#pragma unroll
        for (int n = 0; n < 4; n++) acc[m][n] = MFMA_16x16x32(aF[m], bF[n], acc[m][n]);
    }
  }
#pragma unroll
  for (int m = 0; m < 4; m++) {
#pragma unroll
    for (int n = 0; n < 4; n++) {
      const int col = n0 + wn + n * 16 + lr;
      const float bc = BIAS_ROW ? 0.f : bias[col];
#pragma unroll
      for (int r = 0; r < 4; r++) {
        const int row = m0 + wm + m * 16 + lg * 4 + r;
        float v = acc[m][n][r] + (BIAS_ROW ? bias[row] : bc);
        v = fmaxf(v, 0.f);
        if (OUTF32)
          ((float*)Cout)[(size_t)b * sC + (size_t)row * N + col] = v;
        else
          ((unsigned short*)Cout)[(size_t)b * sC + (size_t)row * N + col] = f2bf(v);
      }
    }
  }
}

// ---------------- fused attention: ctxT = softmax(Q Kt^T /16) @ V ----------------
// NO inter-wave barrier: P rows are wave-private (wave w touches only rows
// w*32..w*32+31); same-wave LDS write->read ordering via lgkmcnt. setprio(1)
// wraps MFMA clusters (pays now that waves phase-diverge).
__global__ __launch_bounds__(256, 4) void attn_kernel(
    const unsigned short* __restrict__ Q, const unsigned short* __restrict__ Kt,
    const unsigned short* __restrict__ Vv, unsigned short* __restrict__ ctxT) {
  const int HW = 16384;
  __shared__ unsigned short Pls[128 * 160];
  const int b = blockIdx.y;
  const int pix0 = blockIdx.x * 128;
  const int tid = threadIdx.x;
  const int w = tid >> 6, l = tid & 63;
  const int lr = l & 15, lg = l >> 4;
  const unsigned short* Qb = Q + ((size_t)b * HW + pix0 + w * 32) * 256;
  const unsigned short* Kb = Kt + (size_t)b * 160 * 256;
  const unsigned short* Vb = Vv + (size_t)b * 256 * 160;
  const f32x4 zero = {0.f, 0.f, 0.f, 0.f};

  f32x4 acc[2][10];
#pragma unroll
  for (int m = 0; m < 2; m++)
#pragma unroll
    for (int n = 0; n < 10; n++) acc[m][n] = zero;
#pragma unroll 2
  for (int ks = 0; ks < 8; ks++) {
    bf16x8 aF[2];
#pragma unroll
    for (int m = 0; m < 2; m++)
      aF[m] = *(const bf16x8*)(Qb + (size_t)(m * 16 + lr) * 256 + ks * 32 + lg * 8);
    __builtin_amdgcn_s_setprio(1);
#pragma unroll
    for (int n = 0; n < 10; n++) {
      bf16x8 bF = *(const bf16x8*)(Kb + (size_t)(n * 16 + lr) * 256 + ks * 32 + lg * 8);
      acc[0][n] = MFMA_16x16x32(aF[0], bF, acc[0][n]);
      acc[1][n] = MFMA_16x16x32(aF[1], bF, acc[1][n]);
    }
    __builtin_amdgcn_s_setprio(0);
  }
  const float scale = 0.0625f;  // 1/sqrt(256)
#pragma unroll
  for (int m = 0; m < 2; m++) {
#pragma unroll
    for (int r = 0; r < 4; r++) {
      float lm = -1e30f;
#pragma unroll
      for (int n = 0; n < 10; n++) {
        float v = acc[m][n][r] * scale;
        acc[m][n][r] = v;
        if (n * 16 + lr < 150) lm = fmaxf(lm, v);
      }
#pragma unroll
      for (int msk = 1; msk <= 8; msk <<= 1) lm = fmaxf(lm, __shfl_xor(lm, msk, 64));
      float s = 0.f;
#pragma unroll
      for (int n = 0; n < 10; n++) {
        float p = (n * 16 + lr < 150) ? __expf(acc[m][n][r] - lm) : 0.f;
        acc[m][n][r] = p;
        s += p;
      }
#pragma unroll
      for (int msk = 1; msk <= 8; msk <<= 1) s += __shfl_xor(s, msk, 64);
      float inv = 1.f / s;
      const int row = w * 32 + m * 16 + lg * 4 + r;
      const unsigned sw = (unsigned)(row & 7) << 4;
#pragma unroll
      for (int n = 0; n < 10; n++) {
        unsigned boff = (unsigned)row * 320 + (unsigned)(n * 16 + lr) * 2;
        *(unsigned short*)((char*)Pls + (boff ^ sw)) = f2bf(acc[m][n][r] * inv);
      }
    }
  }
  // no __syncthreads(): P rows are wave-private; lgkmcnt orders same-wave LDS
  unsigned short* Cb = ctxT + ((size_t)b * HW + pix0 + w * 32) * 256;
#pragma unroll
  for (int half = 0; half < 2; half++) {
    f32x4 acc2[2][8];
#pragma unroll
    for (int m = 0; m < 2; m++)
#pragma unroll
      for (int n = 0; n < 8; n++) acc2[m][n] = zero;
    for (int ks = 0; ks < 5; ks++) {
      bf16x8 aP[2];
#pragma unroll
      for (int m = 0; m < 2; m++) {
        const int row = w * 32 + m * 16 + lr;
        unsigned boff = (unsigned)row * 320 + (unsigned)(ks * 64 + lg * 16);
        aP[m] = *(const bf16x8*)((const char*)Pls + (boff ^ ((unsigned)(row & 7) << 4)));
      }
      __builtin_amdgcn_s_setprio(1);
#pragma unroll
      for (int n = 0; n < 8; n++) {
        const int ch = half * 128 + n * 16 + lr;
        bf16x8 bV = *(const bf16x8*)(Vb + (size_t)ch * 160 + ks * 32 + lg * 8);
        acc2[0][n] = MFMA_16x16x32(aP[0], bV, acc2[0][n]);
        acc2[1][n] = MFMA_16x16x32(aP[1], bV, acc2[1][n]);
      }
      __builtin_amdgcn_s_setprio(0);
    }
#pragma unroll
    for (int m = 0; m < 2; m++)
#pragma unroll
      for (int n = 0; n < 8; n++)
#pragma unroll
        for (int r = 0; r < 4; r++)
          Cb[(size_t)(m * 16 + lg * 4 + r) * 256 + half * 128 + n * 16 + lr] =
              f2bf(acc2[m][n][r]);
  }
}

// ---------------- host launcher ----------------
extern "C" void kernel_launch(void* const* d_in, const int* in_sizes, int n_in,
                              void* d_out, int out_size, void* d_ws, size_t ws_size,
                              hipStream_t stream) {
  (void)in_sizes; (void)n_in; (void)out_size;
  const float* x     = (const float*)d_in[0];
  const float* proxy = (const float*)d_in[1];
  const float* w_fp1 = (const float*)d_in[2];
  const float* b_fp1 = (const float*)d_in[3];
  const float* w_fp2 = (const float*)d_in[4];
  const float* b_fp2 = (const float*)d_in[5];
  const float* w_fo1 = (const float*)d_in[6];
  const float* b_fo1 = (const float*)d_in[7];
  const float* w_fo2 = (const float*)d_in[8];
  const float* b_fo2 = (const float*)d_in[9];
  const float* w_fd  = (const float*)d_in[10];
  const float* b_fd  = (const float*)d_in[11];
  const float* w_fu  = (const float*)d_in[12];
  const float* b_fu  = (const float*)d_in[13];

  char* ws = (char*)d_ws;
  unsigned short* W1b  = (unsigned short*)(ws + 0);          // 256x512 bf16
  unsigned short* W2b  = (unsigned short*)(ws + 262144);     // 256x256
  unsigned short* Wub  = (unsigned short*)(ws + 393216);     // 512x256
  unsigned short* keyT = (unsigned short*)(ws + 655360);     // [8][160][256]
  unsigned short* Vv   = (unsigned short*)(ws + 1310720);    // [8][256][160]
  unsigned short* bufA = (unsigned short*)(ws + 2097152);    // q2T
  unsigned short* bufB = (unsigned short*)(ws + 2097152 + 134217728);  // q1T, later ctxT
  if (ws_size < 203423744) return;

  dim3 blk(256);
  kv_kernel<<<dim3(20, 8), blk, 0, stream>>>(proxy, w_fo1, b_fo1, w_fo2, b_fo2,
                                             w_fd, b_fd, keyT, Vv,
                                             w_fp1, w_fp2, w_fu, W1b, W2b, Wub);
  gemm1_fused<<<dim3(256, 8), blk, 0, stream>>>(x, W1b, b_fp1, bufB);
  gemm_bt_relu<0, 0, 1, 256><<<2048, blk, 0, stream>>>(
      bufB, W2b, b_fp2, bufA, 16384, 256,
      (long long)16384 * 256, 0, (long long)16384 * 256);
  attn_kernel<<<dim3(128, 8), blk, 0, stream>>>(bufA, keyT, Vv, bufB);
  gemm_bt_relu<1, 1, 2, 256><<<4096, blk, 0, stream>>>(
      Wub, bufB, b_fu, d_out, 512, 16384,
      0, (long long)16384 * 256, (long long)512 * 16384);
}